// Round 1
// 2556.807 us; speedup vs baseline: 1.2365x; 1.2365x over previous
//
#include <hip/hip_runtime.h>
#include <cstdint>
#include <cstddef>

#define TT 512
#define BB 64
#define II 256
#define HH 512
#define GG 1536   // 3*H
#define OO 64
#define NWG 256   // scan workgroups: one per CU (forced by LDS ballast)
#define TAGPAD 16 // dwords between tags (64B -> distinct LLC lines)

// ---------------- Phase A: x_proj (unchanged) ----------------
__global__ __launch_bounds__(256)
void xproj_kernel(const float* __restrict__ x, const float* __restrict__ w,
                  const float* __restrict__ xb, float* __restrict__ xp)
{
    __shared__ float xs[64][68];
    __shared__ float ws[64][68];
    const int t  = blockIdx.y;
    const int g0 = blockIdx.x * 64;
    const int tid = threadIdx.x;
    const int gq = tid >> 4;
    const int bq = tid & 15;
    float acc[4][4];
#pragma unroll
    for (int j = 0; j < 4; ++j)
#pragma unroll
        for (int i = 0; i < 4; ++i) acc[j][i] = 0.f;

    for (int kc = 0; kc < 4; ++kc) {
        const int k0 = kc * 64;
        __syncthreads();
        for (int idx = tid; idx < 1024; idx += 256) {
            int r = idx >> 4, c4 = (idx & 15) * 4;
            float4 v = *(const float4*)(x + ((size_t)t * BB + r) * II + k0 + c4);
            xs[r][c4] = v.x; xs[r][c4+1] = v.y; xs[r][c4+2] = v.z; xs[r][c4+3] = v.w;
            float4 u = *(const float4*)(w + (size_t)(g0 + r) * II + k0 + c4);
            ws[r][c4] = u.x; ws[r][c4+1] = u.y; ws[r][c4+2] = u.z; ws[r][c4+3] = u.w;
        }
        __syncthreads();
#pragma unroll 4
        for (int k4 = 0; k4 < 16; ++k4) {
            float4 xv[4], wv[4];
#pragma unroll
            for (int i = 0; i < 4; ++i)
                xv[i] = *(const float4*)&xs[bq + 16*i][k4*4];
#pragma unroll
            for (int j = 0; j < 4; ++j)
                wv[j] = *(const float4*)&ws[gq + 16*j][k4*4];
#pragma unroll
            for (int j = 0; j < 4; ++j)
#pragma unroll
                for (int i = 0; i < 4; ++i) {
                    acc[j][i] = fmaf(wv[j].x, xv[i].x, acc[j][i]);
                    acc[j][i] = fmaf(wv[j].y, xv[i].y, acc[j][i]);
                    acc[j][i] = fmaf(wv[j].z, xv[i].z, acc[j][i]);
                    acc[j][i] = fmaf(wv[j].w, xv[i].w, acc[j][i]);
                }
        }
    }
#pragma unroll
    for (int j = 0; j < 4; ++j) {
        int g = g0 + gq + 16*j;
        float bg = xb[g];
#pragma unroll
        for (int i = 0; i < 4; ++i) {
            int b = bq + 16*i;
            xp[((size_t)t * GG + g) * BB + b] = acc[j][i] + bg;
        }
    }
}

// ---------------- Phase B: XCD-local persistent GRU scan ----------------
// Batch rows partition across XCDs (8 rows/XCD); columns partition across the
// 32 CUs of an XCD (16 cols/WG, wave w owns col pair c0w=16r+2w). All h(t-1)
// a group needs is produced inside its own XCD: h stores are plain
// write-through into the shared per-XCD L2 (fast drain), staged once per step
// into LDS, consumed at LDS BW. Tags stay on the proven sc0|sc1 LLC path
// (vmcnt(0) drain before tag release => tag>=t implies h visible in this L2).
// Group id from HW_REG_XCC_ID; rank via LLC atomic (counter lives in tag
// slot dword 8 -- that line is only ever touched by sc0|sc1 ops + atomics, so
// it never becomes L2-dirty). 86KB LDS ballast forces 1 WG/CU so each XCD
// holds exactly 32 WGs (256 WGs on 256 CUs).
__global__ __launch_bounds__(512, 2)
void scan_kernel(const float* __restrict__ xp, const float* __restrict__ hw,
                 const float* __restrict__ hbias, float* __restrict__ rnn,
                 int* __restrict__ tags)
{
    __shared__ float hlds[8][512];   // h(t-1) for this group's 8 batch rows
    __shared__ float pad_[17408];    // ballast: total ~86KB -> 1 WG/CU
    __shared__ int s_rk;

    const int tid = threadIdx.x;
    ((volatile float*)pad_)[tid] = 0.f;   // keep ballast allocated

    int xcc;
    asm volatile("s_getreg_b32 %0, hwreg(HW_REG_XCC_ID)" : "=s"(xcc));
    const int g = xcc & 7;               // group = physical XCD
    if (tid == 0) {
        __threadfence();                 // one-time L2 wb+inv: drop stale/poison lines
        s_rk = atomicAdd(tags + (size_t)g * 32 * TAGPAD + 8, 1); // rank in XCD
    }
    __syncthreads();
    const int rk = s_rk;
    if (rk >= 32) return;                // cannot happen with 1 WG/CU

    const int w    = tid >> 6;           // wave 0..7: column pair
    const int l    = tid & 63;           // lane: k chunks [4l,4l+4) & [256+4l,+4)
    const int c0w  = rk * 16 + 2 * w;    // wave's first column
    const int cc   = (l >> 3) & 1;
    const int col  = c0w + cc;           // epilogue column (lanes l<16)
    const int ob   = 8 * g + (l & 7);    // epilogue batch row (global)

    // staging map: thread stages 8 contiguous floats of h(t-1)
    const int sb = tid >> 6;             // local batch row 0..7
    const int sk = (tid & 63) * 8;       // k offset

    // weights -> registers: rr = gate*2 + colpick, k split 4l / 256+4l
    float wreg[6][8];
#pragma unroll
    for (int rr = 0; rr < 6; ++rr) {
        const float* wp = hw + ((size_t)(rr >> 1) * HH + c0w + (rr & 1)) * HH;
        float4 a = *(const float4*)(wp + 4 * l);
        float4 b = *(const float4*)(wp + 256 + 4 * l);
        wreg[rr][0] = a.x; wreg[rr][1] = a.y; wreg[rr][2] = a.z; wreg[rr][3] = a.w;
        wreg[rr][4] = b.x; wreg[rr][5] = b.y; wreg[rr][6] = b.z; wreg[rr][7] = b.w;
    }
    const float bhr = hbias[col];
    const float bhu = hbias[HH + col];
    const float bhn = hbias[2 * HH + col];

    float hloc = 0.f;            // lanes l<16: my (b,c) previous h (exact fp32)
    long long budget = 4000000;  // spin bound: bug -> wrong answer, not hang

    for (int t = 0; t < TT; ++t) {
        // xp prefetch (independent of h) - overlaps the tag wait
        float xr = 0.f, xu = 0.f, xn = 0.f;
        if (l < 16) {
            const size_t xbase = (size_t)t * GG * BB;
            xr = xp[xbase + (size_t)(0 * HH + col) * BB + ob];
            xu = xp[xbase + (size_t)(1 * HH + col) * BB + ob];
            xn = xp[xbase + (size_t)(2 * HH + col) * BB + ob];
        }

        float g0v = 0.f, g1v = 0.f, g2v = 0.f;
        if (t > 0) {
            if (tid < 32) {      // one poller per group member
                const int* tp = tags + ((size_t)g * 32 + tid) * TAGPAD;
                int v;
                do {
                    asm volatile("global_load_dword %0, %1, off sc0 sc1\n\t"
                                 "s_waitcnt vmcnt(0)"
                                 : "=v"(v) : "v"(tp) : "memory");
                    if (v >= t) break;
                    __builtin_amdgcn_s_sleep(1);
                } while (--budget > 0);
            }
            __syncthreads(); // B1: all 32 tags seen -> h(t-1) complete in this L2

            // stage h(t-1)[8b][512] (16 KB) into LDS, coalesced from L2
            {
                const float* src = rnn + (size_t)(t - 1) * BB * HH
                                       + (size_t)(8 * g + sb) * HH + sk;
                float4 v0 = *(const float4*)src;
                float4 v1 = *(const float4*)(src + 4);
                *(float4*)&hlds[sb][sk]     = v0;
                *(float4*)&hlds[sb][sk + 4] = v1;
            }
            __syncthreads(); // B2: staging complete

            float acc[8][6];
#pragma unroll
            for (int bi = 0; bi < 8; ++bi) {
                float4 hA = *(const float4*)&hlds[bi][4 * l];
                float4 hB = *(const float4*)&hlds[bi][256 + 4 * l];
#pragma unroll
                for (int rr = 0; rr < 6; ++rr) {
                    float a;
                    a = hA.x * wreg[rr][0];
                    a = fmaf(hA.y, wreg[rr][1], a);
                    a = fmaf(hA.z, wreg[rr][2], a);
                    a = fmaf(hA.w, wreg[rr][3], a);
                    a = fmaf(hB.x, wreg[rr][4], a);
                    a = fmaf(hB.y, wreg[rr][5], a);
                    a = fmaf(hB.z, wreg[rr][6], a);
                    a = fmaf(hB.w, wreg[rr][7], a);
                    acc[bi][rr] = a;
                }
            }

            // transpose-reduce over k (all 64 lanes), identical to verified r3
            const int s0 = l & 1, s1 = (l >> 1) & 1, s2 = (l >> 2) & 1;
            const int s3 = (l >> 3) & 1;
            float a1[4][6];
#pragma unroll
            for (int rr = 0; rr < 6; ++rr)
#pragma unroll
                for (int p = 0; p < 4; ++p) {
                    float lo = acc[2*p][rr], hi = acc[2*p+1][rr];
                    float send = s0 ? lo : hi;
                    float keep = s0 ? hi : lo;
                    a1[p][rr] = keep + __shfl_xor(send, 1, 64);
                }
            float a2[2][6];
#pragma unroll
            for (int rr = 0; rr < 6; ++rr)
#pragma unroll
                for (int p = 0; p < 2; ++p) {
                    float lo = a1[2*p][rr], hi = a1[2*p+1][rr];
                    float send = s1 ? lo : hi;
                    float keep = s1 ? hi : lo;
                    a2[p][rr] = keep + __shfl_xor(send, 2, 64);
                }
            float a3[6];
#pragma unroll
            for (int rr = 0; rr < 6; ++rr) {
                float lo = a2[0][rr], hi = a2[1][rr];
                float send = s2 ? lo : hi;
                float keep = s2 ? hi : lo;
                a3[rr] = keep + __shfl_xor(send, 4, 64);
            }
#pragma unroll
            for (int gate = 0; gate < 3; ++gate) {
                float lo = a3[2*gate], hi = a3[2*gate + 1];
                float send = s3 ? lo : hi;
                float keep = s3 ? hi : lo;
                float gv = keep + __shfl_xor(send, 8, 64);
                if (gate == 0) g0v = gv; else if (gate == 1) g1v = gv; else g2v = gv;
            }
            g0v += __shfl_xor(g0v, 16, 64); g0v += __shfl_xor(g0v, 32, 64);
            g1v += __shfl_xor(g1v, 16, 64); g1v += __shfl_xor(g1v, 32, 64);
            g2v += __shfl_xor(g2v, 16, 64); g2v += __shfl_xor(g2v, 32, 64);
        }

        if (l < 16) { // one lane per output (b=ob, c=col)
            float rg = 1.f / (1.f + __expf(-(xr + g0v + bhr)));
            float ug = 1.f / (1.f + __expf(-(xu + g1v + bhu)));
            // h2h bias of n-gate sits INSIDE reset*(...), per reference
            float npre = xn + rg * (g2v + bhn);
            float e  = __expf(-2.f * npre);
            float nv = 2.f / (1.f + e) - 1.f;
            float hy = ug * hloc + (1.f - ug) * nv;
            hloc = hy;
            float* dst = rnn + ((size_t)t * BB + ob) * HH + col;
            // plain store: write-through into this XCD's L2 (fast drain;
            // all consumers share this L2)
            asm volatile("global_store_dword %0, %1, off"
                         :: "v"(dst), "v"(hy) : "memory");
        }
        asm volatile("s_waitcnt vmcnt(0)" ::: "memory"); // h landed in L2
        __syncthreads(); // B3: all waves' stores drained
        if (tid == 0) {
            int tv = t + 1;
            int* tp = tags + ((size_t)g * 32 + rk) * TAGPAD;
            asm volatile("global_store_dword %0, %1, off sc0 sc1"
                         :: "v"(tp), "v"(tv) : "memory");
        }
    }
}

// ---------------- Phase C: fc output (unchanged) ----------------
__global__ __launch_bounds__(256)
void fc_kernel(const float* __restrict__ rnn, const float* __restrict__ fcw,
               const float* __restrict__ fcb, float* __restrict__ out)
{
    __shared__ float wlds[128][65];
    const int t = blockIdx.x;
    const int tid = threadIdx.x;
    const int o  = tid & 63;
    const int bg = tid >> 6;
    float acc[16];
#pragma unroll
    for (int i = 0; i < 16; ++i) acc[i] = 0.f;

    for (int kc = 0; kc < 4; ++kc) {
        const int k0 = kc * 128;
        __syncthreads();
        for (int idx = tid; idx < 64 * 32; idx += 256) {
            int oo = idx >> 5, kq = (idx & 31) * 4;
            float4 v = *(const float4*)(fcw + (size_t)oo * HH + k0 + kq);
            wlds[kq][oo] = v.x; wlds[kq+1][oo] = v.y;
            wlds[kq+2][oo] = v.z; wlds[kq+3][oo] = v.w;
        }
        __syncthreads();
#pragma unroll 2
        for (int k4 = 0; k4 < 32; ++k4) {
            float w0 = wlds[k4*4+0][o], w1 = wlds[k4*4+1][o];
            float w2 = wlds[k4*4+2][o], w3 = wlds[k4*4+3][o];
#pragma unroll
            for (int i = 0; i < 16; ++i) {
                int bb = bg * 16 + i;
                float4 h4 = *(const float4*)(rnn + ((size_t)t * BB + bb) * HH + k0 + k4*4);
                acc[i] = fmaf(h4.x, w0, fmaf(h4.y, w1, fmaf(h4.z, w2, fmaf(h4.w, w3, acc[i]))));
            }
        }
    }
    float bo = fcb[o];
#pragma unroll
    for (int i = 0; i < 16; ++i) {
        int bb = bg * 16 + i;
        out[((size_t)t * BB + bb) * OO + o] = acc[i] + bo;
    }
}

extern "C" void kernel_launch(void* const* d_in, const int* in_sizes, int n_in,
                              void* d_out, int out_size, void* d_ws, size_t ws_size,
                              hipStream_t stream)
{
    const float* x     = (const float*)d_in[0];
    const float* x2h_w = (const float*)d_in[1];
    const float* x2h_b = (const float*)d_in[2];
    const float* h2h_w = (const float*)d_in[3];
    const float* h2h_b = (const float*)d_in[4];
    const float* fc_w  = (const float*)d_in[5];
    const float* fc_b  = (const float*)d_in[6];

    float* out = (float*)d_out;                        // [T][B][O]
    float* rnn = (float*)d_out + (size_t)TT * BB * OO; // [T][B][H]

    float* xp = (float*)d_ws;                          // [T][3H][B] fp32
    const size_t xp_bytes = (size_t)TT * GG * BB * sizeof(float);
    int* tags = (int*)((char*)d_ws + xp_bytes);        // 8 groups x 32 ranks
                                                       // (+rank counters @ dword 8)

    hipMemsetAsync(tags, 0, NWG * TAGPAD * sizeof(int), stream);

    dim3 gA(GG / 64, TT);
    xproj_kernel<<<gA, 256, 0, stream>>>(x, x2h_w, x2h_b, xp);
    scan_kernel<<<NWG, 512, 0, stream>>>(xp, h2h_w, h2h_b, rnn, tags);
    fc_kernel<<<TT, 256, 0, stream>>>(rnn, fc_w, fc_b, out);
}

// Round 2
// 2494.173 us; speedup vs baseline: 1.2675x; 1.0251x over previous
//
#include <hip/hip_runtime.h>
#include <cstdint>
#include <cstddef>

#define TT 512
#define BB 64
#define II 256
#define HH 512
#define GG 1536   // 3*H
#define OO 64
#define NWG 256   // scan workgroups: one per CU (forced by LDS ballast)
#define TAGPAD 16 // dwords between tags (64B -> distinct LLC lines)

// ---------------- Phase A: x_proj (unchanged) ----------------
__global__ __launch_bounds__(256)
void xproj_kernel(const float* __restrict__ x, const float* __restrict__ w,
                  const float* __restrict__ xb, float* __restrict__ xp)
{
    __shared__ float xs[64][68];
    __shared__ float ws[64][68];
    const int t  = blockIdx.y;
    const int g0 = blockIdx.x * 64;
    const int tid = threadIdx.x;
    const int gq = tid >> 4;
    const int bq = tid & 15;
    float acc[4][4];
#pragma unroll
    for (int j = 0; j < 4; ++j)
#pragma unroll
        for (int i = 0; i < 4; ++i) acc[j][i] = 0.f;

    for (int kc = 0; kc < 4; ++kc) {
        const int k0 = kc * 64;
        __syncthreads();
        for (int idx = tid; idx < 1024; idx += 256) {
            int r = idx >> 4, c4 = (idx & 15) * 4;
            float4 v = *(const float4*)(x + ((size_t)t * BB + r) * II + k0 + c4);
            xs[r][c4] = v.x; xs[r][c4+1] = v.y; xs[r][c4+2] = v.z; xs[r][c4+3] = v.w;
            float4 u = *(const float4*)(w + (size_t)(g0 + r) * II + k0 + c4);
            ws[r][c4] = u.x; ws[r][c4+1] = u.y; ws[r][c4+2] = u.z; ws[r][c4+3] = u.w;
        }
        __syncthreads();
#pragma unroll 4
        for (int k4 = 0; k4 < 16; ++k4) {
            float4 xv[4], wv[4];
#pragma unroll
            for (int i = 0; i < 4; ++i)
                xv[i] = *(const float4*)&xs[bq + 16*i][k4*4];
#pragma unroll
            for (int j = 0; j < 4; ++j)
                wv[j] = *(const float4*)&ws[gq + 16*j][k4*4];
#pragma unroll
            for (int j = 0; j < 4; ++j)
#pragma unroll
                for (int i = 0; i < 4; ++i) {
                    acc[j][i] = fmaf(wv[j].x, xv[i].x, acc[j][i]);
                    acc[j][i] = fmaf(wv[j].y, xv[i].y, acc[j][i]);
                    acc[j][i] = fmaf(wv[j].z, xv[i].z, acc[j][i]);
                    acc[j][i] = fmaf(wv[j].w, xv[i].w, acc[j][i]);
                }
        }
    }
#pragma unroll
    for (int j = 0; j < 4; ++j) {
        int g = g0 + gq + 16*j;
        float bg = xb[g];
#pragma unroll
        for (int i = 0; i < 4; ++i) {
            int b = bq + 16*i;
            xp[((size_t)t * GG + g) * BB + b] = acc[j][i] + bg;
        }
    }
}

// ---------------- Phase B: XCD-local persistent GRU scan ----------------
// 1024 threads = 16 waves/CU (4/SIMD). Wave = (colpair cp, batch-half bh):
// cp in [0,8) -> cols {rk*16+2cp, +1}; bh in {0,1} -> local b in [4bh,4bh+4).
// Lane l: k-slices [4l,4l+4) and [256+4l,..). Per lane: acc[4][6] = 192 FMA
// (half the serial depth of the 512-thread version), same 48-float weight
// file, 8 LDS b128 reads. Transpose-reduce: b-bit0, b-bit1, col-split, then
// 3 butterflies (masks 8/16/32) -> 30 shuffles/lane. Staging: 1 contiguous
// float4/thread (conflict-free). Exchange protocol identical to the verified
// version: plain h stores into the shared per-XCD L2, vmcnt(0) drain,
// sc0|sc1 tags at LLC, 32 pollers; group id = HW_REG_XCC_ID, rank via LLC
// atomic in tag slot dword 8; 86KB LDS ballast forces 1 WG/CU.
__global__ __launch_bounds__(1024, 4)
void scan_kernel(const float* __restrict__ xp, const float* __restrict__ hw,
                 const float* __restrict__ hbias, float* __restrict__ rnn,
                 int* __restrict__ tags)
{
    __shared__ float hlds[8][512];   // h(t-1) for this group's 8 batch rows
    __shared__ float pad_[17408];    // ballast: total ~86KB -> 1 WG/CU
    __shared__ int s_rk;

    const int tid = threadIdx.x;
    ((volatile float*)pad_)[tid] = 0.f;   // keep ballast allocated

    int xcc;
    asm volatile("s_getreg_b32 %0, hwreg(HW_REG_XCC_ID)" : "=s"(xcc));
    const int g = xcc & 7;               // group = physical XCD
    if (tid == 0) {
        __threadfence();                 // one-time: drop stale/poison lines
        s_rk = atomicAdd(tags + (size_t)g * 32 * TAGPAD + 8, 1); // rank in XCD
    }
    __syncthreads();
    const int rk = s_rk;
    if (rk >= 32) return;                // cannot happen with 1 WG/CU

    const int w    = tid >> 6;           // wave 0..15
    const int l    = tid & 63;           // lane
    const int cp   = w >> 1;             // column pair 0..7
    const int bh   = w & 1;              // batch half 0..1
    const int c0w  = rk * 16 + 2 * cp;   // wave's first column
    const int col  = c0w + ((l >> 2) & 1);   // epilogue column (lanes l<8)
    const int ob   = 8 * g + 4 * bh + (l & 3); // epilogue batch row (global)

    // staging map: thread stages 4 contiguous floats of h(t-1)
    const int sb = tid >> 7;             // local batch row 0..7
    const int sk = (tid & 127) * 4;      // k offset

    // weights -> registers: rr = gate*2 + c, k split 4l / 256+4l
    float wreg[6][8];
#pragma unroll
    for (int rr = 0; rr < 6; ++rr) {
        const float* wp = hw + ((size_t)(rr >> 1) * HH + c0w + (rr & 1)) * HH;
        float4 a = *(const float4*)(wp + 4 * l);
        float4 b = *(const float4*)(wp + 256 + 4 * l);
        wreg[rr][0] = a.x; wreg[rr][1] = a.y; wreg[rr][2] = a.z; wreg[rr][3] = a.w;
        wreg[rr][4] = b.x; wreg[rr][5] = b.y; wreg[rr][6] = b.z; wreg[rr][7] = b.w;
    }
    const float bhr = hbias[col];
    const float bhu = hbias[HH + col];
    const float bhn = hbias[2 * HH + col];

    float hloc = 0.f;            // lanes l<8: my (b,c) previous h (exact fp32)
    long long budget = 4000000;  // spin bound: bug -> wrong answer, not hang

    for (int t = 0; t < TT; ++t) {
        // xp prefetch (independent of h) - overlaps the tag wait
        float xr = 0.f, xu = 0.f, xn = 0.f;
        if (l < 8) {
            const size_t xbase = (size_t)t * GG * BB;
            xr = xp[xbase + (size_t)(0 * HH + col) * BB + ob];
            xu = xp[xbase + (size_t)(1 * HH + col) * BB + ob];
            xn = xp[xbase + (size_t)(2 * HH + col) * BB + ob];
        }

        float g0v = 0.f, g1v = 0.f, g2v = 0.f;
        if (t > 0) {
            if (tid < 32) {      // one poller per group member
                const int* tp = tags + ((size_t)g * 32 + tid) * TAGPAD;
                int v;
                do {
                    asm volatile("global_load_dword %0, %1, off sc0 sc1\n\t"
                                 "s_waitcnt vmcnt(0)"
                                 : "=v"(v) : "v"(tp) : "memory");
                    if (v >= t) break;
                    __builtin_amdgcn_s_sleep(1);
                } while (--budget > 0);
            }
            __syncthreads(); // B1: all 32 tags seen -> h(t-1) complete in this L2

            // stage h(t-1)[8b][512] (16 KB) into LDS, coalesced from L2
            {
                const float* src = rnn + (size_t)(t - 1) * BB * HH
                                       + (size_t)(8 * g + sb) * HH + sk;
                *(float4*)&hlds[sb][sk] = *(const float4*)src;
            }
            __syncthreads(); // B2: staging complete

            // matvec: 4 b x 6 (gate,col) x 8 k = 192 FMA
            float acc[4][6];
#pragma unroll
            for (int bi = 0; bi < 4; ++bi) {
                float4 hA = *(const float4*)&hlds[4 * bh + bi][4 * l];
                float4 hB = *(const float4*)&hlds[4 * bh + bi][256 + 4 * l];
#pragma unroll
                for (int rr = 0; rr < 6; ++rr) {
                    float a;
                    a = hA.x * wreg[rr][0];
                    a = fmaf(hA.y, wreg[rr][1], a);
                    a = fmaf(hA.z, wreg[rr][2], a);
                    a = fmaf(hA.w, wreg[rr][3], a);
                    a = fmaf(hB.x, wreg[rr][4], a);
                    a = fmaf(hB.y, wreg[rr][5], a);
                    a = fmaf(hB.z, wreg[rr][6], a);
                    a = fmaf(hB.w, wreg[rr][7], a);
                    acc[bi][rr] = a;
                }
            }

            // transpose-reduce over k
            const int s0 = l & 1, s1 = (l >> 1) & 1, s2 = (l >> 2) & 1;
            // round 1 (b bit0, mask 1)
            float a1[2][6];
#pragma unroll
            for (int rr = 0; rr < 6; ++rr)
#pragma unroll
                for (int p = 0; p < 2; ++p) {
                    float lo = acc[2*p][rr], hi = acc[2*p+1][rr];
                    float send = s0 ? lo : hi;
                    float keep = s0 ? hi : lo;
                    a1[p][rr] = keep + __shfl_xor(send, 1, 64);
                }
            // round 2 (b bit1, mask 2)
            float a2[6];
#pragma unroll
            for (int rr = 0; rr < 6; ++rr) {
                float lo = a1[0][rr], hi = a1[1][rr];
                float send = s1 ? lo : hi;
                float keep = s1 ? hi : lo;
                a2[rr] = keep + __shfl_xor(send, 2, 64);
            }
            // round 3 (col split, mask 4)
            float a3[3];
#pragma unroll
            for (int gate = 0; gate < 3; ++gate) {
                float lo = a2[2*gate], hi = a2[2*gate + 1];
                float send = s2 ? lo : hi;
                float keep = s2 ? hi : lo;
                a3[gate] = keep + __shfl_xor(send, 4, 64);
            }
            // rounds 4..6: plain butterflies (masks 8,16,32) -> full k-sum
            g0v = a3[0]; g1v = a3[1]; g2v = a3[2];
            g0v += __shfl_xor(g0v, 8, 64); g0v += __shfl_xor(g0v, 16, 64); g0v += __shfl_xor(g0v, 32, 64);
            g1v += __shfl_xor(g1v, 8, 64); g1v += __shfl_xor(g1v, 16, 64); g1v += __shfl_xor(g1v, 32, 64);
            g2v += __shfl_xor(g2v, 8, 64); g2v += __shfl_xor(g2v, 16, 64); g2v += __shfl_xor(g2v, 32, 64);
        }

        if (l < 8) { // one lane per output (b=ob, c=col)
            float rg = 1.f / (1.f + __expf(-(xr + g0v + bhr)));
            float ug = 1.f / (1.f + __expf(-(xu + g1v + bhu)));
            // h2h bias of n-gate sits INSIDE reset*(...), per reference
            float npre = xn + rg * (g2v + bhn);
            float e  = __expf(-2.f * npre);
            float nv = 2.f / (1.f + e) - 1.f;
            float hy = ug * hloc + (1.f - ug) * nv;
            hloc = hy;
            float* dst = rnn + ((size_t)t * BB + ob) * HH + col;
            // plain store: write-through into this XCD's L2 (fast drain;
            // all consumers share this L2)
            asm volatile("global_store_dword %0, %1, off"
                         :: "v"(dst), "v"(hy) : "memory");
        }
        asm volatile("s_waitcnt vmcnt(0)" ::: "memory"); // h landed in L2
        __syncthreads(); // B3: all waves' stores drained
        if (tid == 0) {
            int tv = t + 1;
            int* tp = tags + ((size_t)g * 32 + rk) * TAGPAD;
            asm volatile("global_store_dword %0, %1, off sc0 sc1"
                         :: "v"(tp), "v"(tv) : "memory");
        }
    }
}

// ---------------- Phase C: fc output (unchanged) ----------------
__global__ __launch_bounds__(256)
void fc_kernel(const float* __restrict__ rnn, const float* __restrict__ fcw,
               const float* __restrict__ fcb, float* __restrict__ out)
{
    __shared__ float wlds[128][65];
    const int t = blockIdx.x;
    const int tid = threadIdx.x;
    const int o  = tid & 63;
    const int bg = tid >> 6;
    float acc[16];
#pragma unroll
    for (int i = 0; i < 16; ++i) acc[i] = 0.f;

    for (int kc = 0; kc < 4; ++kc) {
        const int k0 = kc * 128;
        __syncthreads();
        for (int idx = tid; idx < 64 * 32; idx += 256) {
            int oo = idx >> 5, kq = (idx & 31) * 4;
            float4 v = *(const float4*)(fcw + (size_t)oo * HH + k0 + kq);
            wlds[kq][oo] = v.x; wlds[kq+1][oo] = v.y;
            wlds[kq+2][oo] = v.z; wlds[kq+3][oo] = v.w;
        }
        __syncthreads();
#pragma unroll 2
        for (int k4 = 0; k4 < 32; ++k4) {
            float w0 = wlds[k4*4+0][o], w1 = wlds[k4*4+1][o];
            float w2 = wlds[k4*4+2][o], w3 = wlds[k4*4+3][o];
#pragma unroll
            for (int i = 0; i < 16; ++i) {
                int bb = bg * 16 + i;
                float4 h4 = *(const float4*)(rnn + ((size_t)t * BB + bb) * HH + k0 + k4*4);
                acc[i] = fmaf(h4.x, w0, fmaf(h4.y, w1, fmaf(h4.z, w2, fmaf(h4.w, w3, acc[i]))));
            }
        }
    }
    float bo = fcb[o];
#pragma unroll
    for (int i = 0; i < 16; ++i) {
        int bb = bg * 16 + i;
        out[((size_t)t * BB + bb) * OO + o] = acc[i] + bo;
    }
}

extern "C" void kernel_launch(void* const* d_in, const int* in_sizes, int n_in,
                              void* d_out, int out_size, void* d_ws, size_t ws_size,
                              hipStream_t stream)
{
    const float* x     = (const float*)d_in[0];
    const float* x2h_w = (const float*)d_in[1];
    const float* x2h_b = (const float*)d_in[2];
    const float* h2h_w = (const float*)d_in[3];
    const float* h2h_b = (const float*)d_in[4];
    const float* fc_w  = (const float*)d_in[5];
    const float* fc_b  = (const float*)d_in[6];

    float* out = (float*)d_out;                        // [T][B][O]
    float* rnn = (float*)d_out + (size_t)TT * BB * OO; // [T][B][H]

    float* xp = (float*)d_ws;                          // [T][3H][B] fp32
    const size_t xp_bytes = (size_t)TT * GG * BB * sizeof(float);
    int* tags = (int*)((char*)d_ws + xp_bytes);        // 8 groups x 32 ranks
                                                       // (+rank counters @ dword 8)

    hipMemsetAsync(tags, 0, NWG * TAGPAD * sizeof(int), stream);

    dim3 gA(GG / 64, TT);
    xproj_kernel<<<gA, 256, 0, stream>>>(x, x2h_w, x2h_b, xp);
    scan_kernel<<<NWG, 1024, 0, stream>>>(xp, h2h_w, h2h_b, rnn, tags);
    fc_kernel<<<TT, 256, 0, stream>>>(rnn, fc_w, fc_b, out);
}